// Round 2
// baseline (43120.572 us; speedup 1.0000x reference)
//
#include <hip/hip_runtime.h>
#include <hip/hip_bf16.h>
#include <hip/hip_cooperative_groups.h>

namespace cg = cooperative_groups;

#define Bb 128
#define Tt 512
#define Dd 1024
#define Hh 1024
#define KD 2048
#define CCH 32               // time steps per chunk
#define NCHUNK (Tt / CCH)    // 16

typedef __attribute__((ext_vector_type(4))) float f32x4;
typedef __attribute__((ext_vector_type(8))) short s16x8;

__device__ __forceinline__ unsigned short f2bf(float f) {
    union { float f; unsigned u; } v;
    v.f = f;
    unsigned r = v.u + 0x7fffu + ((v.u >> 16) & 1u);
    return (unsigned short)(r >> 16);
}

__device__ __forceinline__ s16x8 cvt8(const float* src) {
    f32x4 a = *reinterpret_cast<const f32x4*>(src);
    f32x4 b = *reinterpret_cast<const f32x4*>(src + 4);
    s16x8 v;
    v[0] = (short)f2bf(a[0]); v[1] = (short)f2bf(a[1]);
    v[2] = (short)f2bf(a[2]); v[3] = (short)f2bf(a[3]);
    v[4] = (short)f2bf(b[0]); v[5] = (short)f2bf(b[1]);
    v[6] = (short)f2bf(b[2]); v[7] = (short)f2bf(b[3]);
    return v;
}

// ---------------------------------------------------------------------------
// Zx chunk GEMM: Zxc[b*CCH+tc][n] = sum_k X[b][t0+tc][k] * Wr[n][k] + bre[n]
// M = 4096 (=B*CCH), N = 4096, K = 1024 (x-part of Wr). 128x128 tiles.
// ---------------------------------------------------------------------------
__global__ __launch_bounds__(256) void zx_gemm(
    const float* __restrict__ X, const unsigned short* __restrict__ Wr,
    const float* __restrict__ bre, float* __restrict__ Zxc, int t0)
{
    __shared__ __align__(16) unsigned short ALds[2][128 * 64];
    __shared__ __align__(16) unsigned short BLds[2][128 * 64];

    const int tid = threadIdx.x, lane = tid & 63, wv = tid >> 6;
    const int wr = wv >> 1, wc = wv & 1;
    const int m0 = (blockIdx.x >> 5) * 128, n0 = (blockIdx.x & 31) * 128;

    f32x4 acc[4][4];
#pragma unroll
    for (int i = 0; i < 4; ++i)
#pragma unroll
        for (int jn = 0; jn < 4; ++jn) acc[i][jn] = 0.f;

    auto stage = [&](int buf, int ki) {
        const int k0 = ki * 64;
#pragma unroll
        for (int i = 0; i < 4; ++i) {
            int slot = i * 256 + tid;            // 1024 slots of 8 bf16
            int r = slot >> 3, cp = slot & 7;
            int c = cp ^ (r & 7);
            int m = m0 + r, b = m >> 5, tc = m & 31;
            const float* src = X + ((size_t)b * Tt + t0 + tc) * Dd + k0 + c * 8;
            *reinterpret_cast<s16x8*>(&ALds[buf][slot * 8]) = cvt8(src);
        }
#pragma unroll
        for (int i = 0; i < 4; ++i) {
            int slot = i * 256 + tid;
            int r = slot >> 3, cp = slot & 7;
            int c = cp ^ (r & 7);
            const unsigned short* src = Wr + (size_t)(n0 + r) * KD + k0 + c * 8;
            *reinterpret_cast<s16x8*>(&BLds[buf][slot * 8]) =
                *reinterpret_cast<const s16x8*>(src);
        }
    };

    auto compute = [&](int buf) {
#pragma unroll
        for (int ks = 0; ks < 2; ++ks) {
            int ck = ks * 4 + (lane >> 4);
            s16x8 af[4], bf8[4];
#pragma unroll
            for (int m = 0; m < 4; ++m) {
                int ra = wr * 64 + m * 16 + (lane & 15);
                af[m] = *reinterpret_cast<const s16x8*>(&ALds[buf][ra * 64 + (ck ^ (ra & 7)) * 8]);
            }
#pragma unroll
            for (int n = 0; n < 4; ++n) {
                int rb = wc * 64 + n * 16 + (lane & 15);
                bf8[n] = *reinterpret_cast<const s16x8*>(&BLds[buf][rb * 64 + (ck ^ (rb & 7)) * 8]);
            }
#pragma unroll
            for (int m = 0; m < 4; ++m)
#pragma unroll
                for (int n = 0; n < 4; ++n)
                    acc[m][n] = __builtin_amdgcn_mfma_f32_16x16x32_bf16(af[m], bf8[n], acc[m][n], 0, 0, 0);
        }
    };

    stage(0, 0);
#pragma unroll 1
    for (int ki = 0; ki < 16; ++ki) {
        __syncthreads();
        if (ki + 1 < 16) stage((ki + 1) & 1, ki + 1);
        compute(ki & 1);
    }

#pragma unroll
    for (int ni = 0; ni < 4; ++ni) {
        int gcol = n0 + wc * 64 + ni * 16 + (lane & 15);
        float bias = bre[gcol];
#pragma unroll
        for (int mi = 0; mi < 4; ++mi) {
            int rbase = m0 + wr * 64 + mi * 16 + (lane >> 4) * 4;
#pragma unroll
            for (int r = 0; r < 4; ++r)
                Zxc[(size_t)(rbase + r) * 4096 + gcol] = acc[mi][ni][r] + bias;
        }
    }
}

// ---------------------------------------------------------------------------
// Persistent recurrent kernel: CCH steps of h@Wh + gates, grid-synced.
// 256 blocks = 128 col-groups x 2 batch-halves; Wh panel (64KB) in LDS.
// ---------------------------------------------------------------------------
__global__ __launch_bounds__(256) void lstm_seq(
    const float* __restrict__ Zxc, const unsigned short* __restrict__ Wr,
    unsigned short* __restrict__ hbuf, float* __restrict__ cbuf,
    float* __restrict__ out, int t0)
{
    __shared__ __align__(16) unsigned short Wh[32 * 1032];   // 129 chunks/row (pad 1)
    __shared__ __align__(16) unsigned short Alds[2][64 * 64];
    __shared__ float zlds[64 * 33];

    const int tid = threadIdx.x, lane = tid & 63, w = tid >> 6;
    const int g = blockIdx.x >> 1, mh = blockIdx.x & 1;
    cg::grid_group grid = cg::this_grid();

    // Load Wh panel once: rows n = g*32..+32, k = h-part (cols 1024..2048 of Wr)
#pragma unroll
    for (int i = 0; i < 16; ++i) {
        int q = i * 256 + tid;           // 4096 data chunks of 16B
        int n = q >> 7, ck = q & 127;
        int pos = (ck & ~7) | ((ck ^ (n & 7)) & 7);
        *reinterpret_cast<s16x8*>(&Wh[n * 1032 + pos * 8]) =
            *reinterpret_cast<const s16x8*>(Wr + (size_t)(g * 32 + n) * KD + Dd + ck * 8);
    }

    // persistent cell state in registers (thread owns 2 (row,col) cells)
    const int row0 = tid >> 3, jj = tid & 7;
    const int row1 = row0 + 32;
    const int j = g * 8 + jj;
    float c0 = cbuf[(size_t)(mh * 64 + row0) * Hh + j];
    float c1 = cbuf[(size_t)(mh * 64 + row1) * Hh + j];
    __syncthreads();

#pragma unroll 1
    for (int t = t0; t < t0 + CCH; ++t) {
        const int p = t & 1;
        const unsigned short* hin = hbuf + (size_t)p * (Bb * Hh);
        unsigned short* hout = hbuf + (size_t)(1 - p) * (Bb * Hh);

        f32x4 acc[2];
        acc[0] = 0.f; acc[1] = 0.f;

        auto stageA = [&](int buf, int ki) {
#pragma unroll
            for (int i = 0; i < 2; ++i) {
                int slot = i * 256 + tid;        // 512 slots
                int r = slot >> 3, cp = slot & 7;
                int c = cp ^ (r & 7);
                *reinterpret_cast<s16x8*>(&Alds[buf][slot * 8]) =
                    *reinterpret_cast<const s16x8*>(hin + (size_t)(mh * 64 + r) * Hh + ki * 64 + c * 8);
            }
        };

        auto compute = [&](int buf, int ki) {
#pragma unroll
            for (int ks = 0; ks < 2; ++ks) {
                int ra = w * 16 + (lane & 15);
                int cka = ks * 4 + (lane >> 4);
                s16x8 af = *reinterpret_cast<const s16x8*>(&Alds[buf][ra * 64 + ((cka ^ (ra & 7)) * 8)]);
#pragma unroll
                for (int nt = 0; nt < 2; ++nt) {
                    int n = nt * 16 + (lane & 15);
                    int pos = ki * 8 + ((ks * 4 + (lane >> 4)) ^ (n & 7));
                    s16x8 bf8 = *reinterpret_cast<const s16x8*>(&Wh[n * 1032 + pos * 8]);
                    acc[nt] = __builtin_amdgcn_mfma_f32_16x16x32_bf16(af, bf8, acc[nt], 0, 0, 0);
                }
            }
        };

        stageA(0, 0);
#pragma unroll 1
        for (int ki = 0; ki < 16; ++ki) {
            __syncthreads();
            if (ki + 1 < 16) stageA((ki + 1) & 1, ki + 1);
            compute(ki & 1, ki);
        }

        {   // dump z to LDS (D-layout: col=lane&15, row=(lane>>4)*4+reg)
            int rbase = w * 16 + (lane >> 4) * 4;
#pragma unroll
            for (int nt = 0; nt < 2; ++nt) {
                int col = nt * 16 + (lane & 15);
#pragma unroll
                for (int r = 0; r < 4; ++r)
                    zlds[(rbase + r) * 33 + col] = acc[nt][r];
            }
        }
        __syncthreads();

#pragma unroll
        for (int it = 0; it < 2; ++it) {
            int row = it ? row1 : row0;
            int grow = mh * 64 + row;
            const float* Zxr = Zxc + ((size_t)grow * CCH + (t - t0)) * 4096 + g * 32;
            float zf = zlds[row * 33 + jj]      + Zxr[jj];
            float zi = zlds[row * 33 + 8 + jj]  + Zxr[8 + jj];
            float zo = zlds[row * 33 + 16 + jj] + Zxr[16 + jj];
            float zc = zlds[row * 33 + 24 + jj] + Zxr[24 + jj];
            float fg = 1.f / (1.f + __expf(-zf));
            float ig = 1.f / (1.f + __expf(-zi));
            float og = 1.f / (1.f + __expf(-zo));
            float gg = tanhf(zc);
            float cold = it ? c1 : c0;
            float cnew = fg * cold + ig * gg;
            if (it) c1 = cnew; else c0 = cnew;
            float hn = og * tanhf(cnew);
            hout[(size_t)grow * Hh + j] = f2bf(hn);
            out[((size_t)grow * Tt + (Tt - 1 - t)) * Hh + j] = hn;
        }

        __threadfence();
        grid.sync();
        __threadfence();
    }

    cbuf[(size_t)(mh * 64 + row0) * Hh + j] = c0;
    cbuf[(size_t)(mh * 64 + row1) * Hh + j] = c1;
}

// ---------------------------------------------------------------------------
// Weight reorg + reordered bias: Wr[n][k] bf16, n = g*32 + gate*8 + jj.
// ---------------------------------------------------------------------------
__global__ void conv_w(const float* __restrict__ Wf, const float* __restrict__ Wi,
                       const float* __restrict__ Wo, const float* __restrict__ Wc,
                       const float* __restrict__ bF, const float* __restrict__ bI,
                       const float* __restrict__ bO, const float* __restrict__ bC,
                       unsigned short* __restrict__ Wr, float* __restrict__ bre) {
    int n = blockIdx.x;                  // 0..4095
    int g = n >> 5, rem = n & 31, gate = rem >> 3, jj = rem & 7;
    int col = g * 8 + jj;
    const float* Wg = (gate == 0) ? Wf : (gate == 1) ? Wi : (gate == 2) ? Wo : Wc;
#pragma unroll
    for (int i = 0; i < 8; ++i) {
        int k = threadIdx.x + i * 256;
        Wr[(size_t)n * KD + k] = f2bf(Wg[(size_t)k * Hh + col]);
    }
    if (threadIdx.x == 0) {
        const float* bg = (gate == 0) ? bF : (gate == 1) ? bI : (gate == 2) ? bO : bC;
        bre[n] = bg[col];
    }
}

__global__ void init_state(unsigned short* __restrict__ h0, float* __restrict__ c0) {
    int i = blockIdx.x * 256 + threadIdx.x;
    if (i < Bb * Hh) { h0[i] = 0; c0[i] = 0.f; }
}

// ---------------------------------------------------------------------------
// Fallback path (round-1, proven): one fused kernel per time step.
// ---------------------------------------------------------------------------
__global__ __launch_bounds__(256) void lstm_step(
    const float* __restrict__ X, const unsigned short* __restrict__ Wr,
    const float* __restrict__ bre,
    const unsigned short* __restrict__ hin, unsigned short* __restrict__ hout,
    float* __restrict__ cbuf, float* __restrict__ out, int t)
{
    __shared__ __align__(16) unsigned short Alds[2][64 * 64];
    __shared__ __align__(16) unsigned short Blds[2][32 * 64];
    __shared__ float zlds[64 * 33];

    const int tid = threadIdx.x, lane = tid & 63, w = tid >> 6;
    const int g = blockIdx.x >> 1, mh = blockIdx.x & 1;

    f32x4 acc[2];
    acc[0] = 0.f; acc[1] = 0.f;

    auto stageA = [&](int buf, int ki) {
        const int k0 = ki * 64;
#pragma unroll
        for (int i = 0; i < 2; ++i) {
            int slot = tid + 256 * i;
            int r = slot >> 3, cp = slot & 7;
            int c = cp ^ (r & 7);
            int k = k0 + c * 8;
            s16x8 v;
            if (k < Dd) {
                v = cvt8(X + ((size_t)(mh * 64 + r) * Tt + t) * Dd + k);
            } else {
                v = *reinterpret_cast<const s16x8*>(hin + (size_t)(mh * 64 + r) * Hh + (k - Dd));
            }
            *reinterpret_cast<s16x8*>(&Alds[buf][slot * 8]) = v;
        }
    };
    auto stageB = [&](int buf, int ki) {
        int n = tid >> 3, cp = tid & 7;
        int c = cp ^ (n & 7);
        const unsigned short* src = Wr + (size_t)(g * 32 + n) * KD + ki * 64 + c * 8;
        *reinterpret_cast<s16x8*>(&Blds[buf][tid * 8]) = *reinterpret_cast<const s16x8*>(src);
    };
    auto compute = [&](int buf) {
#pragma unroll
        for (int ks = 0; ks < 2; ++ks) {
            int ra = w * 16 + (lane & 15);
            int cha = (ks * 4 + (lane >> 4)) ^ (ra & 7);
            s16x8 af = *reinterpret_cast<const s16x8*>(&Alds[buf][ra * 64 + cha * 8]);
#pragma unroll
            for (int nt = 0; nt < 2; ++nt) {
                int n = nt * 16 + (lane & 15);
                int chb = (ks * 4 + (lane >> 4)) ^ (n & 7);
                s16x8 bf8 = *reinterpret_cast<const s16x8*>(&Blds[buf][n * 64 + chb * 8]);
                acc[nt] = __builtin_amdgcn_mfma_f32_16x16x32_bf16(af, bf8, acc[nt], 0, 0, 0);
            }
        }
    };

    stageA(0, 0); stageB(0, 0);
#pragma unroll 1
    for (int ki = 0; ki < 32; ++ki) {
        __syncthreads();
        if (ki + 1 < 32) { stageA((ki + 1) & 1, ki + 1); stageB((ki + 1) & 1, ki + 1); }
        compute(ki & 1);
    }

    {
        int rbase = w * 16 + (lane >> 4) * 4;
#pragma unroll
        for (int nt = 0; nt < 2; ++nt) {
            int col = nt * 16 + (lane & 15);
#pragma unroll
            for (int r = 0; r < 4; ++r)
                zlds[(rbase + r) * 33 + col] = acc[nt][r];
        }
    }
    __syncthreads();

#pragma unroll
    for (int it = 0; it < 2; ++it) {
        int idx = tid + it * 256;
        int row = idx >> 3, jj = idx & 7;
        int jx = g * 8 + jj;
        int grow = mh * 64 + row;
        float zf = zlds[row * 33 + jj]      + bre[g * 32 + jj];
        float zi = zlds[row * 33 + 8 + jj]  + bre[g * 32 + 8 + jj];
        float zo = zlds[row * 33 + 16 + jj] + bre[g * 32 + 16 + jj];
        float zc = zlds[row * 33 + 24 + jj] + bre[g * 32 + 24 + jj];
        float fg = 1.f / (1.f + __expf(-zf));
        float ig = 1.f / (1.f + __expf(-zi));
        float og = 1.f / (1.f + __expf(-zo));
        float gg = tanhf(zc);
        float cold = cbuf[(size_t)grow * Hh + jx];
        float cnew = fg * cold + ig * gg;
        cbuf[(size_t)grow * Hh + jx] = cnew;
        float hn = og * tanhf(cnew);
        hout[(size_t)grow * Hh + jx] = f2bf(hn);
        out[((size_t)grow * Tt + (Tt - 1 - t)) * Hh + jx] = hn;
    }
}

extern "C" void kernel_launch(void* const* d_in, const int* in_sizes, int n_in,
                              void* d_out, int out_size, void* d_ws, size_t ws_size,
                              hipStream_t stream) {
    (void)in_sizes; (void)n_in; (void)out_size;
    const float* X  = (const float*)d_in[0];
    const float* Wf = (const float*)d_in[1];
    const float* bF = (const float*)d_in[2];
    const float* Wi = (const float*)d_in[3];
    const float* bI = (const float*)d_in[4];
    const float* Wo = (const float*)d_in[5];
    const float* bO = (const float*)d_in[6];
    const float* Wc = (const float*)d_in[7];
    const float* bC = (const float*)d_in[8];
    float* out = (float*)d_out;

    char* ws = (char*)d_ws;
    size_t off = 0;
    auto carve = [&](size_t sz) { char* p = ws + off; off = (off + sz + 255) & ~(size_t)255; return p; };
    unsigned short* Wr   = (unsigned short*)carve((size_t)4096 * KD * 2);      // 16 MB
    float*          bre  = (float*)carve(4096 * 4);                            // 16 KB
    float*          Zxc  = (float*)carve((size_t)4096 * 4096 * 4);             // 64 MB
    unsigned short* hbuf = (unsigned short*)carve((size_t)2 * Bb * Hh * 2);    // 512 KB
    float*          cbuf = (float*)carve((size_t)Bb * Hh * 4);                 // 512 KB
    const size_t need = off;

    conv_w<<<4096, 256, 0, stream>>>(Wf, Wi, Wo, Wc, bF, bI, bO, bC, Wr, bre);
    init_state<<<(Bb * Hh + 255) / 256, 256, 0, stream>>>(hbuf, cbuf);

    if (ws_size >= need) {
        const float* Zxc_c = Zxc;
        const unsigned short* Wr_c = Wr;
        for (int c = 0; c < NCHUNK; ++c) {
            int t0 = c * CCH;
            zx_gemm<<<1024, 256, 0, stream>>>(X, Wr, bre, Zxc, t0);
            void* args[] = {(void*)&Zxc_c, (void*)&Wr_c, (void*)&hbuf,
                            (void*)&cbuf, (void*)&out, (void*)&t0};
            hipLaunchCooperativeKernel((void*)lstm_seq, dim3(256), dim3(256), args, 0, stream);
        }
    } else {
        // fallback: per-step fused kernels (round-1 path)
        for (int t = 0; t < Tt; ++t) {
            const unsigned short* hin = hbuf + (size_t)(t & 1) * Bb * Hh;
            unsigned short*      hout = hbuf + (size_t)((t + 1) & 1) * Bb * Hh;
            lstm_step<<<256, 256, 0, stream>>>(X, Wr, bre, hin, hout, cbuf, out, t);
        }
    }
}

// Round 3
// 8380.123 us; speedup vs baseline: 5.1456x; 5.1456x over previous
//
#include <hip/hip_runtime.h>
#include <hip/hip_bf16.h>

#define Bb 128
#define Tt 512
#define Dd 1024
#define Hh 1024
#define KD 2048
#define CCH 32               // time steps per Zx chunk
#define NCHUNK (Tt / CCH)    // 16

typedef __attribute__((ext_vector_type(4))) float f32x4;
typedef __attribute__((ext_vector_type(8))) short s16x8;
typedef __attribute__((address_space(1))) const void gcvoid;
typedef __attribute__((address_space(3))) void lvoid;

__device__ __forceinline__ unsigned short f2bf(float f) {
    union { float f; unsigned u; } v;
    v.f = f;
    unsigned r = v.u + 0x7fffu + ((v.u >> 16) & 1u);
    return (unsigned short)(r >> 16);
}

__device__ __forceinline__ s16x8 cvt8(const float* src) {
    f32x4 a = *reinterpret_cast<const f32x4*>(src);
    f32x4 b = *reinterpret_cast<const f32x4*>(src + 4);
    s16x8 v;
    v[0] = (short)f2bf(a[0]); v[1] = (short)f2bf(a[1]);
    v[2] = (short)f2bf(a[2]); v[3] = (short)f2bf(a[3]);
    v[4] = (short)f2bf(b[0]); v[5] = (short)f2bf(b[1]);
    v[6] = (short)f2bf(b[2]); v[7] = (short)f2bf(b[3]);
    return v;
}

__device__ __forceinline__ float sigf(float x)      { return 1.f / (1.f + __expf(-x)); }
__device__ __forceinline__ float tanhfast(float x)  { return 1.f - 2.f / (1.f + __expf(2.f * x)); }

// ---------------------------------------------------------------------------
// Zx chunk GEMM: M=4096 (B*CCH), N=4096, K=1024 (x-part). Output GATE-PACKED:
// Zxc[(b*CCH+tc)*4096 + j*4 + gate]  (j = h-col 0..1023, gate = f,i,o,g)
// ---------------------------------------------------------------------------
__global__ __launch_bounds__(256) void zx_gemm(
    const float* __restrict__ X, const unsigned short* __restrict__ Wr,
    const float* __restrict__ bre, float* __restrict__ Zxc, int t0)
{
    __shared__ __align__(16) unsigned short ALds[2][128 * 64];
    __shared__ __align__(16) unsigned short BLds[2][128 * 64];

    const int tid = threadIdx.x, lane = tid & 63, wv = tid >> 6;
    const int wr = wv >> 1, wc = wv & 1;
    const int m0 = (blockIdx.x >> 5) * 128, n0 = (blockIdx.x & 31) * 128;

    f32x4 acc[4][4];
#pragma unroll
    for (int i = 0; i < 4; ++i)
#pragma unroll
        for (int jn = 0; jn < 4; ++jn) acc[i][jn] = 0.f;

    auto stage = [&](int buf, int ki) {
        const int k0 = ki * 64;
#pragma unroll
        for (int i = 0; i < 4; ++i) {
            int slot = i * 256 + tid;            // 1024 slots of 8 bf16
            int r = slot >> 3, cp = slot & 7;
            int c = cp ^ (r & 7);
            int m = m0 + r, b = m >> 5, tc = m & 31;
            const float* src = X + ((size_t)b * Tt + t0 + tc) * Dd + k0 + c * 8;
            *reinterpret_cast<s16x8*>(&ALds[buf][slot * 8]) = cvt8(src);
        }
#pragma unroll
        for (int i = 0; i < 4; ++i) {
            int slot = i * 256 + tid;
            int r = slot >> 3, cp = slot & 7;
            int c = cp ^ (r & 7);
            const unsigned short* src = Wr + (size_t)(n0 + r) * KD + k0 + c * 8;
            *reinterpret_cast<s16x8*>(&BLds[buf][slot * 8]) =
                *reinterpret_cast<const s16x8*>(src);
        }
    };

    auto compute = [&](int buf) {
#pragma unroll
        for (int ks = 0; ks < 2; ++ks) {
            int ck = ks * 4 + (lane >> 4);
            s16x8 af[4], bf8[4];
#pragma unroll
            for (int m = 0; m < 4; ++m) {
                int ra = wr * 64 + m * 16 + (lane & 15);
                af[m] = *reinterpret_cast<const s16x8*>(&ALds[buf][ra * 64 + (ck ^ (ra & 7)) * 8]);
            }
#pragma unroll
            for (int n = 0; n < 4; ++n) {
                int rb = wc * 64 + n * 16 + (lane & 15);
                bf8[n] = *reinterpret_cast<const s16x8*>(&BLds[buf][rb * 64 + (ck ^ (rb & 7)) * 8]);
            }
#pragma unroll
            for (int m = 0; m < 4; ++m)
#pragma unroll
                for (int n = 0; n < 4; ++n)
                    acc[m][n] = __builtin_amdgcn_mfma_f32_16x16x32_bf16(af[m], bf8[n], acc[m][n], 0, 0, 0);
        }
    };

    stage(0, 0);
#pragma unroll 1
    for (int ki = 0; ki < 16; ++ki) {
        __syncthreads();
        if (ki + 1 < 16) stage((ki + 1) & 1, ki + 1);
        compute(ki & 1);
    }

#pragma unroll
    for (int ni = 0; ni < 4; ++ni) {
        int gcol = n0 + wc * 64 + ni * 16 + (lane & 15);
        float bias = bre[gcol];
        int gg = gcol >> 5, nn = gcol & 31;
        int zcol = gg * 32 + (nn & 7) * 4 + (nn >> 3);     // gate-packed column
#pragma unroll
        for (int mi = 0; mi < 4; ++mi) {
            int rbase = m0 + wr * 64 + mi * 16 + (lane >> 4) * 4;
#pragma unroll
            for (int r = 0; r < 4; ++r)
                Zxc[(size_t)(rbase + r) * 4096 + zcol] = acc[mi][ni][r] + bias;
        }
    }
}

// ---------------------------------------------------------------------------
// Per-step recurrent kernel (launch boundary = barrier). 256 blocks =
// 128 col-groups x 2 batch-halves; 4 waves; wave = 16 rows x 32 z-cols.
// z = h @ Wh  (K=1024), gates via shfl_xor(8), c in global fp32.
// ---------------------------------------------------------------------------
__global__ __launch_bounds__(256) void lstm_step2(
    const unsigned short* __restrict__ Wr,
    const float* __restrict__ Zxc,
    const unsigned short* __restrict__ hin,
    unsigned short* __restrict__ hout,
    float* __restrict__ cbuf,
    float* __restrict__ out, int t)
{
    __shared__ __align__(16) unsigned short Bl[32 * 1024];   // 64 KB Wh slice

    const int tid = threadIdx.x, lane = tid & 63, w = tid >> 6;
    const int g = blockIdx.x >> 1, mh = blockIdx.x & 1;

    // Stage Wh slice: linear LDS dest, XOR-swizzled global source (m173).
#pragma unroll
    for (int i = 0; i < 16; ++i) {
        int q = (w * 16 + i) * 64 + lane;        // chunk index 0..4095
        int n = q >> 7, cp = q & 127;
        int cs = (cp & ~7) | ((cp ^ n) & 7);
        const unsigned short* src = Wr + (size_t)(g * 32 + n) * KD + Dd + cs * 8;
        __builtin_amdgcn_global_load_lds((gcvoid*)src,
            (lvoid*)&Bl[(w * 16 + i) * 512], 16, 0, 0);
    }
    asm volatile("s_waitcnt vmcnt(0)" ::: "memory");
    __syncthreads();

    const int r0 = mh * 64 + w * 16 + (lane & 15);
    const unsigned short* arow = hin + (size_t)r0 * Hh + (lane >> 4) * 8;
    const int nlo = lane & 15;
    const unsigned short* b0p = &Bl[nlo * 1024];

    f32x4 acc0 = 0.f, acc1 = 0.f;
#pragma unroll 8
    for (int ki = 0; ki < 32; ++ki) {
        s16x8 af = *reinterpret_cast<const s16x8*>(arow + ki * 32);
        int ck = ki * 4 + (lane >> 4);
        int p  = (ck & ~7) | ((ck ^ nlo) & 7);
        s16x8 b0 = *reinterpret_cast<const s16x8*>(b0p + p * 8);
        s16x8 b1 = *reinterpret_cast<const s16x8*>(b0p + 16 * 1024 + p * 8);
        acc0 = __builtin_amdgcn_mfma_f32_16x16x32_bf16(af, b0, acc0, 0, 0, 0);
        acc1 = __builtin_amdgcn_mfma_f32_16x16x32_bf16(af, b1, acc1, 0, 0, 0);
    }

    // acc0 cols = gates {f,i}, acc1 cols = gates {o,g}; pair-exchange via shfl.
    const int jj = lane & 7, j = g * 8 + jj;
    const bool hi = (lane & 8) != 0;
    f32x4 y0, y1;
#pragma unroll
    for (int r = 0; r < 4; ++r) {
        y0[r] = __shfl_xor(acc0[r], 8, 64);
        y1[r] = __shfl_xor(acc1[r], 8, 64);
    }
#pragma unroll
    for (int r = 0; r < 4; ++r) {
        float vf = hi ? y0[r] : acc0[r];
        float vi = hi ? acc0[r] : y0[r];
        float vo = hi ? y1[r] : acc1[r];
        float vg = hi ? acc1[r] : y1[r];
        int row = mh * 64 + w * 16 + (lane >> 4) * 4 + r;
        f32x4 zx = *reinterpret_cast<const f32x4*>(
            Zxc + ((size_t)row * CCH + (t & (CCH - 1))) * 4096 + j * 4);
        float zf = vf + zx[0], zi = vi + zx[1], zo = vo + zx[2], zc = vg + zx[3];
        float fg = sigf(zf), ig = sigf(zi), og = sigf(zo), gv = tanhfast(zc);
        float cold = cbuf[(size_t)row * Hh + j];
        float cnew = fg * cold + ig * gv;
        cbuf[(size_t)row * Hh + j] = cnew;       // dup lanes write same value
        float hn = og * tanhfast(cnew);
        hout[(size_t)row * Hh + j] = f2bf(hn);
        out[((size_t)row * Tt + (Tt - 1 - t)) * Hh + j] = hn;
    }
}

// ---------------------------------------------------------------------------
// Weight reorg + reordered bias: Wr[n][k] bf16, n = g*32 + gate*8 + jj.
// ---------------------------------------------------------------------------
__global__ void conv_w(const float* __restrict__ Wf, const float* __restrict__ Wi,
                       const float* __restrict__ Wo, const float* __restrict__ Wc,
                       const float* __restrict__ bF, const float* __restrict__ bI,
                       const float* __restrict__ bO, const float* __restrict__ bC,
                       unsigned short* __restrict__ Wr, float* __restrict__ bre) {
    int n = blockIdx.x;                  // 0..4095
    int g = n >> 5, rem = n & 31, gate = rem >> 3, jj = rem & 7;
    int col = g * 8 + jj;
    const float* Wg = (gate == 0) ? Wf : (gate == 1) ? Wi : (gate == 2) ? Wo : Wc;
#pragma unroll
    for (int i = 0; i < 8; ++i) {
        int k = threadIdx.x + i * 256;
        Wr[(size_t)n * KD + k] = f2bf(Wg[(size_t)k * Hh + col]);
    }
    if (threadIdx.x == 0) {
        const float* bg = (gate == 0) ? bF : (gate == 1) ? bI : (gate == 2) ? bO : bC;
        bre[n] = bg[col];
    }
}

__global__ void init_state(unsigned short* __restrict__ h0, float* __restrict__ c0) {
    int i = blockIdx.x * 256 + threadIdx.x;
    if (i < Bb * Hh) { h0[i] = 0; c0[i] = 0.f; }
}

// ---------------------------------------------------------------------------
// Fallback path (round-1, proven): one fused kernel per time step, K=2048.
// Uses plain bias vector bre (no Zx).
// ---------------------------------------------------------------------------
__global__ __launch_bounds__(256) void lstm_step(
    const float* __restrict__ X, const unsigned short* __restrict__ Wr,
    const float* __restrict__ bre,
    const unsigned short* __restrict__ hin, unsigned short* __restrict__ hout,
    float* __restrict__ cbuf, float* __restrict__ out, int t)
{
    __shared__ __align__(16) unsigned short Alds[2][64 * 64];
    __shared__ __align__(16) unsigned short Blds[2][32 * 64];
    __shared__ float zlds[64 * 33];

    const int tid = threadIdx.x, lane = tid & 63, w = tid >> 6;
    const int g = blockIdx.x >> 1, mh = blockIdx.x & 1;

    f32x4 acc[2];
    acc[0] = 0.f; acc[1] = 0.f;

    auto stageA = [&](int buf, int ki) {
        const int k0 = ki * 64;
#pragma unroll
        for (int i = 0; i < 2; ++i) {
            int slot = tid + 256 * i;
            int r = slot >> 3, cp = slot & 7;
            int c = cp ^ (r & 7);
            int k = k0 + c * 8;
            s16x8 v;
            if (k < Dd) {
                v = cvt8(X + ((size_t)(mh * 64 + r) * Tt + t) * Dd + k);
            } else {
                v = *reinterpret_cast<const s16x8*>(hin + (size_t)(mh * 64 + r) * Hh + (k - Dd));
            }
            *reinterpret_cast<s16x8*>(&Alds[buf][slot * 8]) = v;
        }
    };
    auto stageB = [&](int buf, int ki) {
        int n = tid >> 3, cp = tid & 7;
        int c = cp ^ (n & 7);
        const unsigned short* src = Wr + (size_t)(g * 32 + n) * KD + ki * 64 + c * 8;
        *reinterpret_cast<s16x8*>(&Blds[buf][tid * 8]) = *reinterpret_cast<const s16x8*>(src);
    };
    auto compute = [&](int buf) {
#pragma unroll
        for (int ks = 0; ks < 2; ++ks) {
            int ra = w * 16 + (lane & 15);
            int cha = (ks * 4 + (lane >> 4)) ^ (ra & 7);
            s16x8 af = *reinterpret_cast<const s16x8*>(&Alds[buf][ra * 64 + cha * 8]);
#pragma unroll
            for (int nt = 0; nt < 2; ++nt) {
                int n = nt * 16 + (lane & 15);
                int chb = (ks * 4 + (lane >> 4)) ^ (n & 7);
                s16x8 bf8 = *reinterpret_cast<const s16x8*>(&Blds[buf][n * 64 + chb * 8]);
                acc[nt] = __builtin_amdgcn_mfma_f32_16x16x32_bf16(af, bf8, acc[nt], 0, 0, 0);
            }
        }
    };

    stageA(0, 0); stageB(0, 0);
#pragma unroll 1
    for (int ki = 0; ki < 32; ++ki) {
        __syncthreads();
        if (ki + 1 < 32) { stageA((ki + 1) & 1, ki + 1); stageB((ki + 1) & 1, ki + 1); }
        compute(ki & 1);
    }

    {
        int rbase = w * 16 + (lane >> 4) * 4;
#pragma unroll
        for (int nt = 0; nt < 2; ++nt) {
            int col = nt * 16 + (lane & 15);
#pragma unroll
            for (int r = 0; r < 4; ++r)
                zlds[(rbase + r) * 33 + col] = acc[nt][r];
        }
    }
    __syncthreads();

#pragma unroll
    for (int it = 0; it < 2; ++it) {
        int idx = tid + it * 256;
        int row = idx >> 3, jj = idx & 7;
        int jx = g * 8 + jj;
        int grow = mh * 64 + row;
        float zf = zlds[row * 33 + jj]      + bre[g * 32 + jj];
        float zi = zlds[row * 33 + 8 + jj]  + bre[g * 32 + 8 + jj];
        float zo = zlds[row * 33 + 16 + jj] + bre[g * 32 + 16 + jj];
        float zc = zlds[row * 33 + 24 + jj] + bre[g * 32 + 24 + jj];
        float fg = sigf(zf), ig = sigf(zi), og = sigf(zo), gv = tanhfast(zc);
        float cold = cbuf[(size_t)grow * Hh + jx];
        float cnew = fg * cold + ig * gv;
        cbuf[(size_t)grow * Hh + jx] = cnew;
        float hn = og * tanhfast(cnew);
        hout[(size_t)grow * Hh + jx] = f2bf(hn);
        out[((size_t)grow * Tt + (Tt - 1 - t)) * Hh + jx] = hn;
    }
}

extern "C" void kernel_launch(void* const* d_in, const int* in_sizes, int n_in,
                              void* d_out, int out_size, void* d_ws, size_t ws_size,
                              hipStream_t stream) {
    (void)in_sizes; (void)n_in; (void)out_size;
    const float* X  = (const float*)d_in[0];
    const float* Wf = (const float*)d_in[1];
    const float* bF = (const float*)d_in[2];
    const float* Wi = (const float*)d_in[3];
    const float* bI = (const float*)d_in[4];
    const float* Wo = (const float*)d_in[5];
    const float* bO = (const float*)d_in[6];
    const float* Wc = (const float*)d_in[7];
    const float* bC = (const float*)d_in[8];
    float* out = (float*)d_out;

    char* ws = (char*)d_ws;
    size_t off = 0;
    auto carve = [&](size_t sz) { char* p = ws + off; off = (off + sz + 255) & ~(size_t)255; return p; };
    unsigned short* Wr   = (unsigned short*)carve((size_t)4096 * KD * 2);      // 16 MB
    float*          bre  = (float*)carve(4096 * 4);                            // 16 KB
    float*          Zxc  = (float*)carve((size_t)4096 * 4096 * 4);             // 64 MB
    unsigned short* hbuf = (unsigned short*)carve((size_t)2 * Bb * Hh * 2);    // 512 KB
    float*          cbuf = (float*)carve((size_t)Bb * Hh * 4);                 // 512 KB
    const size_t need = off;

    conv_w<<<4096, 256, 0, stream>>>(Wf, Wi, Wo, Wc, bF, bI, bO, bC, Wr, bre);
    init_state<<<(Bb * Hh + 255) / 256, 256, 0, stream>>>(hbuf, cbuf);

    if (ws_size >= need) {
        for (int c = 0; c < NCHUNK; ++c) {
            zx_gemm<<<1024, 256, 0, stream>>>(X, Wr, bre, Zxc, c * CCH);
            for (int tt = 0; tt < CCH; ++tt) {
                int t = c * CCH + tt;
                const unsigned short* hin = hbuf + (size_t)(t & 1) * (Bb * Hh);
                unsigned short*      hout = hbuf + (size_t)((t + 1) & 1) * (Bb * Hh);
                lstm_step2<<<256, 256, 0, stream>>>(Wr, Zxc, hin, hout, cbuf, out, t);
            }
        }
    } else {
        for (int t = 0; t < Tt; ++t) {
            const unsigned short* hin = hbuf + (size_t)(t & 1) * Bb * Hh;
            unsigned short*      hout = hbuf + (size_t)((t + 1) & 1) * Bb * Hh;
            lstm_step<<<256, 256, 0, stream>>>(X, Wr, bre, hin, hout, cbuf, out, t);
        }
    }
}